// Round 1
// baseline (1641.152 us; speedup 1.0000x reference)
//
#include <hip/hip_runtime.h>
#include <hip/hip_bf16.h>
#include <math.h>

// GCN forward: 4 GraphConv layers + sum-pool + 2-layer FC head + softmax.
// N_NODES=100000, N_EDGES=3200000, N_GRAPHS=64, IN=128, DIM=32.

#define DIMF 32

// ---------------- Layer 0: A = x@Wn0 ; B = x@Ws0 + bn0 ----------------
// block = 256 threads = 8 nodes x 32 feats; each block covers 64 nodes.
__global__ __launch_bounds__(256) void k_layer0(
    const float* __restrict__ x, const float* __restrict__ Wn0,
    const float* __restrict__ bn0, const float* __restrict__ Ws0,
    float* __restrict__ A, float* __restrict__ B, int n_nodes)
{
    __shared__ float sWn[128 * 32];
    __shared__ float sWs[128 * 32];
    __shared__ float sx[8 * 128];

    for (int i = threadIdx.x; i < 128 * 32; i += 256) {
        sWn[i] = Wn0[i];
        sWs[i] = Ws0[i];
    }
    const int j  = threadIdx.x & 31;
    const int ln = threadIdx.x >> 5;
    const float bias = bn0[j];
    __syncthreads();

    const int base = blockIdx.x * 64;
    for (int g = 0; g < 8; ++g) {
        const int nb = base + g * 8;
        __syncthreads();   // protect sx reuse across iterations
        {
            // 8 rows x 128 floats = 1024 floats = 256 x float4, coalesced
            const int t   = threadIdx.x;
            const int row = nb + (t >> 5);
            if (row < n_nodes) {
                const float4* s4 = (const float4*)(x + (size_t)row * 128);
                ((float4*)sx)[t] = s4[t & 31];
            }
        }
        __syncthreads();
        const int node = nb + ln;
        if (node < n_nodes) {
            float accA = 0.f, accB = bias;
#pragma unroll
            for (int k = 0; k < 128; ++k) {
                const float xv = sx[ln * 128 + k];
                accA += xv * sWn[k * 32 + j];
                accB += xv * sWs[k * 32 + j];
            }
            A[(size_t)node * 32 + j] = accA;
            B[(size_t)node * 32 + j] = accB;
        }
    }
}

// ------------- Layers 1..3: A = relu(H)@Wn ; B = relu(H)@Ws + bn -------------
__global__ __launch_bounds__(256) void k_layer(
    const float* __restrict__ Hpre, const float* __restrict__ Wn,
    const float* __restrict__ bnv, const float* __restrict__ Ws,
    float* __restrict__ A, float* __restrict__ B, int n_nodes)
{
    __shared__ float sWn[32 * 32];
    __shared__ float sWs[32 * 32];
    __shared__ float sh[8 * 32];

    for (int i = threadIdx.x; i < 1024; i += 256) {
        sWn[i] = Wn[i];
        sWs[i] = Ws[i];
    }
    const int j  = threadIdx.x & 31;
    const int ln = threadIdx.x >> 5;
    const float bias = bnv[j];
    __syncthreads();

    const int base = blockIdx.x * 64;
    for (int g = 0; g < 8; ++g) {
        const int nb = base + g * 8;
        __syncthreads();
        {
            const int row = nb + (threadIdx.x >> 5);
            if (row < n_nodes)
                sh[threadIdx.x] = fmaxf(Hpre[(size_t)nb * 32 + threadIdx.x], 0.f);
        }
        __syncthreads();
        const int node = nb + ln;
        if (node < n_nodes) {
            float accA = 0.f, accB = bias;
#pragma unroll
            for (int k = 0; k < 32; ++k) {
                const float hv = sh[ln * 32 + k];
                accA += hv * sWn[k * 32 + j];
                accB += hv * sWs[k * 32 + j];
            }
            A[(size_t)node * 32 + j] = accA;
            B[(size_t)node * 32 + j] = accB;
        }
    }
}

// ---------------- Edge scatter: B[dst] += A[src], 32 lanes/edge ----------------
__global__ __launch_bounds__(256) void k_scatter(
    const int* __restrict__ src, const int* __restrict__ dst,
    const float* __restrict__ A, float* __restrict__ B, int n_edges)
{
    const long long gid = (long long)blockIdx.x * 256 + threadIdx.x;
    const int e = (int)(gid >> 5);
    if (e >= n_edges) return;
    const int j = (int)(gid & 31);
    const int s = src[e];
    const int d = dst[e];
    atomicAdd(&B[(size_t)d * 32 + j], A[(size_t)s * 32 + j]);
}

// ---------------- Per-graph sum pool: hg[g] = sum relu(H[n]) ----------------
// one block per graph; graph_ids is sorted -> binary search boundaries
__global__ __launch_bounds__(256) void k_pool(
    const float* __restrict__ H, const int* __restrict__ gids,
    float* __restrict__ hg, int n_nodes)
{
    const int g = blockIdx.x;
    int lo = 0, hi = n_nodes;
    while (lo < hi) { int m = (lo + hi) >> 1; if (gids[m] < g) lo = m + 1; else hi = m; }
    const int start = lo;
    hi = n_nodes;
    while (lo < hi) { int m = (lo + hi) >> 1; if (gids[m] < g + 1) lo = m + 1; else hi = m; }
    const int end = lo;

    const int j = threadIdx.x & 31;
    const int s = threadIdx.x >> 5;
    float acc = 0.f;
    for (int n = start + s; n < end; n += 8)
        acc += fmaxf(H[(size_t)n * 32 + j], 0.f);

    __shared__ float red[256];
    red[threadIdx.x] = acc;
    __syncthreads();
    if (s == 0) {
        float t = 0.f;
#pragma unroll
        for (int k = 0; k < 8; ++k) t += red[k * 32 + j];
        hg[g * 32 + j] = t;
    }
}

// ---------------- FC head + softmax: one thread per graph ----------------
__global__ __launch_bounds__(64) void k_head(
    const float* __restrict__ hg,
    const float* __restrict__ Wfc1, const float* __restrict__ bfc1,
    const float* __restrict__ Wout, const float* __restrict__ bout,
    float* __restrict__ out, int n_graphs)
{
    const int g = blockIdx.x * blockDim.x + threadIdx.x;
    if (g >= n_graphs) return;
    float h[32];
#pragma unroll
    for (int k = 0; k < 32; ++k) h[k] = hg[g * 32 + k];
    float z[8];
#pragma unroll
    for (int m = 0; m < 8; ++m) {
        float a = bfc1[m];
#pragma unroll
        for (int k = 0; k < 32; ++k) a += h[k] * Wfc1[k * 8 + m];
        z[m] = fmaxf(a, 0.f);
    }
    float o[4];
#pragma unroll
    for (int q = 0; q < 4; ++q) {
        float a = bout[q];
#pragma unroll
        for (int m = 0; m < 8; ++m) a += z[m] * Wout[m * 4 + q];
        o[q] = fmaxf(a, 0.f);
    }
    const float mx = fmaxf(fmaxf(o[0], o[1]), fmaxf(o[2], o[3]));
    const float e0 = expf(o[0] - mx), e1 = expf(o[1] - mx);
    const float e2 = expf(o[2] - mx), e3 = expf(o[3] - mx);
    const float inv = 1.f / (e0 + e1 + e2 + e3);
    out[g * 4 + 0] = e0 * inv;
    out[g * 4 + 1] = e1 * inv;
    out[g * 4 + 2] = e2 * inv;
    out[g * 4 + 3] = e3 * inv;
}

extern "C" void kernel_launch(void* const* d_in, const int* in_sizes, int n_in,
                              void* d_out, int out_size, void* d_ws, size_t ws_size,
                              hipStream_t stream)
{
    const float* x    = (const float*)d_in[0];
    const float* Wn0  = (const float*)d_in[1];
    const float* bn0  = (const float*)d_in[2];
    const float* Ws0  = (const float*)d_in[3];
    const float* Wn   = (const float*)d_in[4];   // [3,32,32]
    const float* bn   = (const float*)d_in[5];   // [3,32]
    const float* Ws   = (const float*)d_in[6];   // [3,32,32]
    const float* Wfc1 = (const float*)d_in[7];
    const float* bfc1 = (const float*)d_in[8];
    const float* Wout = (const float*)d_in[9];
    const float* bout = (const float*)d_in[10];
    const int*   src  = (const int*)d_in[11];
    const int*   dst  = (const int*)d_in[12];
    const int*   gids = (const int*)d_in[13];

    const int n_nodes  = in_sizes[0] / 128;
    const int n_edges  = in_sizes[11];
    const int n_graphs = out_size / 4;

    float* A  = (float*)d_ws;                       // rhs buffer   [n_nodes,32]
    float* B0 = A  + (size_t)n_nodes * 32;          // acc buffer 0 [n_nodes,32]
    float* B1 = B0 + (size_t)n_nodes * 32;          // acc buffer 1 [n_nodes,32]
    float* hg = B1 + (size_t)n_nodes * 32;          // pooled       [n_graphs,32]

    const int mblocks = (n_nodes + 63) / 64;
    const int sblocks = (int)(((long long)n_edges * 32 + 255) / 256);

    // Layer 0
    k_layer0<<<mblocks, 256, 0, stream>>>(x, Wn0, bn0, Ws0, A, B0, n_nodes);
    k_scatter<<<sblocks, 256, 0, stream>>>(src, dst, A, B0, n_edges);

    // Layers 1..3 (ReLU applied on read of previous pre-activation)
    float* cur = B0;
    float* nxt = B1;
    for (int l = 0; l < 3; ++l) {
        k_layer<<<mblocks, 256, 0, stream>>>(cur, Wn + l * 1024, bn + l * 32,
                                             Ws + l * 1024, A, nxt, n_nodes);
        k_scatter<<<sblocks, 256, 0, stream>>>(src, dst, A, nxt, n_edges);
        float* t = cur; cur = nxt; nxt = t;
    }

    // Pool + head
    k_pool<<<n_graphs, 256, 0, stream>>>(cur, gids, hg, n_nodes);
    k_head<<<(n_graphs + 63) / 64, 64, 0, stream>>>(hg, Wfc1, bfc1, Wout, bout,
                                                    (float*)d_out, n_graphs);
}

// Round 2
// 1229.191 us; speedup vs baseline: 1.3351x; 1.3351x over previous
//
#include <hip/hip_runtime.h>
#include <hip/hip_bf16.h>
#include <math.h>

// GCN forward: 4 GraphConv layers + sum-pool + FC head + softmax.
// N_NODES=100000, N_EDGES=3200000, N_GRAPHS=64, IN=128, DIM=32.
// Strategy: per-call counting-sort edges into CSR (by dst), then each layer's
// aggregation is an atomic-free gather-sum (one 32-lane group per dst node).

#define CHUNK 2048

// ---------------- CSR build ----------------
__global__ __launch_bounds__(256) void k_zero(int* __restrict__ p, int n)
{
    int i = blockIdx.x * 256 + threadIdx.x;
    if (i < n) p[i] = 0;
}

__global__ __launch_bounds__(256) void k_hist(
    const int* __restrict__ dst, int* __restrict__ cnt, int n_edges)
{
    int e = blockIdx.x * 256 + threadIdx.x;
    if (e < n_edges) atomicAdd(&cnt[dst[e]], 1);
}

__global__ __launch_bounds__(256) void k_chunk_sum(
    const int* __restrict__ cnt, int* __restrict__ part, int n)
{
    __shared__ int red[256];
    const int base = blockIdx.x * CHUNK;
    int s = 0;
    for (int i = threadIdx.x; i < CHUNK; i += 256) {
        int idx = base + i;
        if (idx < n) s += cnt[idx];
    }
    red[threadIdx.x] = s;
    __syncthreads();
    for (int off = 128; off > 0; off >>= 1) {
        if (threadIdx.x < off) red[threadIdx.x] += red[threadIdx.x + off];
        __syncthreads();
    }
    if (threadIdx.x == 0) part[blockIdx.x] = red[0];
}

__global__ void k_scan_part(int* __restrict__ part, int nparts)
{
    if (threadIdx.x == 0 && blockIdx.x == 0) {
        int run = 0;
        for (int i = 0; i < nparts; ++i) { int v = part[i]; part[i] = run; run += v; }
    }
}

__global__ __launch_bounds__(256) void k_write_ptr(
    const int* __restrict__ cnt, const int* __restrict__ part,
    int* __restrict__ ptr, int* __restrict__ cursor, int n, int n_edges)
{
    __shared__ int lds[256];
    const int tid   = threadIdx.x;
    const int base  = blockIdx.x * CHUNK;
    const int tbase = base + tid * 8;
    int c[8];
    int tot = 0;
#pragma unroll
    for (int m = 0; m < 8; ++m) {
        int idx = tbase + m;
        c[m] = (idx < n) ? cnt[idx] : 0;
        tot += c[m];
    }
    lds[tid] = tot;
    __syncthreads();
    // inclusive Hillis-Steele scan over 256 thread-totals
    for (int off = 1; off < 256; off <<= 1) {
        int v = (tid >= off) ? lds[tid - off] : 0;
        __syncthreads();
        lds[tid] += v;
        __syncthreads();
    }
    int run = part[blockIdx.x] + lds[tid] - tot;  // exclusive prefix for this thread
#pragma unroll
    for (int m = 0; m < 8; ++m) {
        int idx = tbase + m;
        if (idx < n) { ptr[idx] = run; cursor[idx] = run; }
        run += c[m];
    }
    if (blockIdx.x == 0 && tid == 0) ptr[n] = n_edges;
}

__global__ __launch_bounds__(256) void k_build(
    const int* __restrict__ src, const int* __restrict__ dst,
    int* __restrict__ cursor, int* __restrict__ eidx, int n_edges)
{
    int e = blockIdx.x * 256 + threadIdx.x;
    if (e < n_edges) {
        int d = dst[e];
        int p = atomicAdd(&cursor[d], 1);
        eidx[p] = src[e];
    }
}

// ---------------- Layer 0: A = x@Wn0 ; B = x@Ws0 + bn0 ----------------
// 32-node tile per block; thread (r=tid>>5, j=tid&31) handles nodes r+8m.
__global__ __launch_bounds__(256) void k_layer0(
    const float* __restrict__ x, const float* __restrict__ Wn0,
    const float* __restrict__ bn0, const float* __restrict__ Ws0,
    float* __restrict__ A, float* __restrict__ B, int n_nodes)
{
    __shared__ float sWn[128 * 32];
    __shared__ float sWs[128 * 32];
    __shared__ float sx[32 * 128];

    for (int i = threadIdx.x; i < 128 * 32; i += 256) {
        sWn[i] = Wn0[i];
        sWs[i] = Ws0[i];
    }
    const int tile = blockIdx.x * 32;
    // load 32 rows x 128 = 1024 float4, coalesced (tile assumed full or guarded)
    {
        const float4* s4 = (const float4*)(x + (size_t)tile * 128);
        const int lim = (n_nodes - tile) * 32;  // float4 count available
#pragma unroll
        for (int m = 0; m < 4; ++m) {
            int i = threadIdx.x + m * 256;
            if (i < lim) ((float4*)sx)[i] = s4[i];
        }
    }
    const int j = threadIdx.x & 31;
    const int r = threadIdx.x >> 5;
    const float bias = bn0[j];
    __syncthreads();

    float accA[4] = {0.f, 0.f, 0.f, 0.f};
    float accB[4] = {bias, bias, bias, bias};
#pragma unroll 8
    for (int k = 0; k < 128; ++k) {
        const float wn = sWn[k * 32 + j];
        const float ws = sWs[k * 32 + j];
#pragma unroll
        for (int m = 0; m < 4; ++m) {
            const float xv = sx[(r + 8 * m) * 128 + k];
            accA[m] += xv * wn;
            accB[m] += xv * ws;
        }
    }
#pragma unroll
    for (int m = 0; m < 4; ++m) {
        const int node = tile + r + 8 * m;
        if (node < n_nodes) {
            A[(size_t)node * 32 + j] = accA[m];
            B[(size_t)node * 32 + j] = accB[m];
        }
    }
}

// ------------- Layers 1..3: A = relu(H)@Wn ; B = relu(H)@Ws + bn -------------
// 64-node tile; thread handles nodes r+8m, m=0..7.
__global__ __launch_bounds__(256) void k_layer(
    const float* __restrict__ Hpre, const float* __restrict__ Wn,
    const float* __restrict__ bnv, const float* __restrict__ Ws,
    float* __restrict__ A, float* __restrict__ B, int n_nodes)
{
    __shared__ float sWn[32 * 32];
    __shared__ float sWs[32 * 32];
    __shared__ float sh[64 * 32];

    for (int i = threadIdx.x; i < 1024; i += 256) {
        sWn[i] = Wn[i];
        sWs[i] = Ws[i];
    }
    const int tile = blockIdx.x * 64;
    {
        const float4* s4 = (const float4*)(Hpre + (size_t)tile * 32);
        const int lim = (n_nodes - tile) * 8;  // float4 count available
#pragma unroll
        for (int m = 0; m < 2; ++m) {
            int i = threadIdx.x + m * 256;
            if (i < lim) {
                float4 v = s4[i];
                v.x = fmaxf(v.x, 0.f); v.y = fmaxf(v.y, 0.f);
                v.z = fmaxf(v.z, 0.f); v.w = fmaxf(v.w, 0.f);
                ((float4*)sh)[i] = v;
            }
        }
    }
    const int j = threadIdx.x & 31;
    const int r = threadIdx.x >> 5;
    const float bias = bnv[j];
    __syncthreads();

    float accA[8] = {0.f};
    float accB[8];
#pragma unroll
    for (int m = 0; m < 8; ++m) accB[m] = bias;
#pragma unroll
    for (int k = 0; k < 32; ++k) {
        const float wn = sWn[k * 32 + j];
        const float ws = sWs[k * 32 + j];
#pragma unroll
        for (int m = 0; m < 8; ++m) {
            const float hv = sh[(r + 8 * m) * 32 + k];
            accA[m] += hv * wn;
            accB[m] += hv * ws;
        }
    }
#pragma unroll
    for (int m = 0; m < 8; ++m) {
        const int node = tile + r + 8 * m;
        if (node < n_nodes) {
            A[(size_t)node * 32 + j] = accA[m];
            B[(size_t)node * 32 + j] = accB[m];
        }
    }
}

// ------------- Aggregation: B[d] += sum_{e in CSR[d]} A[eidx[e]] -------------
// one 32-lane group per dst node; coalesced 128 B row loads.
__global__ __launch_bounds__(256) void k_aggregate(
    const int* __restrict__ ptr, const int* __restrict__ eidx,
    const float* __restrict__ A, float* __restrict__ B, int n_nodes)
{
    const int group = (blockIdx.x * 256 + threadIdx.x) >> 5;
    const int j = threadIdx.x & 31;
    if (group >= n_nodes) return;
    const int beg = ptr[group];
    const int end = ptr[group + 1];
    float acc = B[(size_t)group * 32 + j];  // self + bias already present
    int base = beg;
    for (; base + 32 <= end; base += 32) {
        const int myidx = eidx[base + j];
#pragma unroll
        for (int k = 0; k < 32; ++k) {
            const int s = __shfl(myidx, k, 32);
            acc += A[(size_t)s * 32 + j];
        }
    }
    const int rem = end - base;
    if (rem > 0) {
        const int myidx = (base + j < end) ? eidx[base + j] : 0;
        for (int k = 0; k < rem; ++k) {
            const int s = __shfl(myidx, k, 32);
            acc += A[(size_t)s * 32 + j];
        }
    }
    B[(size_t)group * 32 + j] = acc;
}

// ---------------- Per-graph sum pool ----------------
__global__ __launch_bounds__(256) void k_pool(
    const float* __restrict__ H, const int* __restrict__ gids,
    float* __restrict__ hg, int n_nodes)
{
    const int g = blockIdx.x;
    int lo = 0, hi = n_nodes;
    while (lo < hi) { int m = (lo + hi) >> 1; if (gids[m] < g) lo = m + 1; else hi = m; }
    const int start = lo;
    hi = n_nodes;
    while (lo < hi) { int m = (lo + hi) >> 1; if (gids[m] < g + 1) lo = m + 1; else hi = m; }
    const int end = lo;

    const int j = threadIdx.x & 31;
    const int s = threadIdx.x >> 5;
    float acc = 0.f;
    for (int n = start + s; n < end; n += 8)
        acc += fmaxf(H[(size_t)n * 32 + j], 0.f);

    __shared__ float red[256];
    red[threadIdx.x] = acc;
    __syncthreads();
    if (s == 0) {
        float t = 0.f;
#pragma unroll
        for (int k = 0; k < 8; ++k) t += red[k * 32 + j];
        hg[g * 32 + j] = t;
    }
}

// ---------------- FC head + softmax ----------------
__global__ __launch_bounds__(64) void k_head(
    const float* __restrict__ hg,
    const float* __restrict__ Wfc1, const float* __restrict__ bfc1,
    const float* __restrict__ Wout, const float* __restrict__ bout,
    float* __restrict__ out, int n_graphs)
{
    const int g = blockIdx.x * blockDim.x + threadIdx.x;
    if (g >= n_graphs) return;
    float h[32];
#pragma unroll
    for (int k = 0; k < 32; ++k) h[k] = hg[g * 32 + k];
    float z[8];
#pragma unroll
    for (int m = 0; m < 8; ++m) {
        float a = bfc1[m];
#pragma unroll
        for (int k = 0; k < 32; ++k) a += h[k] * Wfc1[k * 8 + m];
        z[m] = fmaxf(a, 0.f);
    }
    float o[4];
#pragma unroll
    for (int q = 0; q < 4; ++q) {
        float a = bout[q];
#pragma unroll
        for (int m = 0; m < 8; ++m) a += z[m] * Wout[m * 4 + q];
        o[q] = fmaxf(a, 0.f);
    }
    const float mx = fmaxf(fmaxf(o[0], o[1]), fmaxf(o[2], o[3]));
    const float e0 = expf(o[0] - mx), e1 = expf(o[1] - mx);
    const float e2 = expf(o[2] - mx), e3 = expf(o[3] - mx);
    const float inv = 1.f / (e0 + e1 + e2 + e3);
    out[g * 4 + 0] = e0 * inv;
    out[g * 4 + 1] = e1 * inv;
    out[g * 4 + 2] = e2 * inv;
    out[g * 4 + 3] = e3 * inv;
}

extern "C" void kernel_launch(void* const* d_in, const int* in_sizes, int n_in,
                              void* d_out, int out_size, void* d_ws, size_t ws_size,
                              hipStream_t stream)
{
    const float* x    = (const float*)d_in[0];
    const float* Wn0  = (const float*)d_in[1];
    const float* bn0  = (const float*)d_in[2];
    const float* Ws0  = (const float*)d_in[3];
    const float* Wn   = (const float*)d_in[4];   // [3,32,32]
    const float* bn   = (const float*)d_in[5];   // [3,32]
    const float* Ws   = (const float*)d_in[6];   // [3,32,32]
    const float* Wfc1 = (const float*)d_in[7];
    const float* bfc1 = (const float*)d_in[8];
    const float* Wout = (const float*)d_in[9];
    const float* bout = (const float*)d_in[10];
    const int*   src  = (const int*)d_in[11];
    const int*   dst  = (const int*)d_in[12];
    const int*   gids = (const int*)d_in[13];

    const int n_nodes  = in_sizes[0] / 128;
    const int n_edges  = in_sizes[11];
    const int n_graphs = out_size / 4;
    const size_t N32 = (size_t)n_nodes * 32;

    float* A    = (float*)d_ws;          // [N,32] rhs
    float* B0   = A + N32;               // [N,32] acc ping
    float* B1   = B0 + N32;              // [N,32] acc pong
    float* hg   = B1 + N32;              // [G,32]
    int* cnt    = (int*)(hg + (size_t)n_graphs * 32);
    int* ptr    = cnt + n_nodes;         // n+1
    int* cursor = ptr + n_nodes + 1;     // n
    int* part   = cursor + n_nodes;      // nparts
    int* eidx   = part + 256;            // [n_edges]

    const int nparts  = (n_nodes + CHUNK - 1) / CHUNK;
    const int eblocks = (n_edges + 255) / 256;
    const int nblocks = (n_nodes + 255) / 256;

    // ---- CSR build (once per call; reused by all 4 layers) ----
    k_zero<<<nblocks, 256, 0, stream>>>(cnt, n_nodes);
    k_hist<<<eblocks, 256, 0, stream>>>(dst, cnt, n_edges);
    k_chunk_sum<<<nparts, 256, 0, stream>>>(cnt, part, n_nodes);
    k_scan_part<<<1, 64, 0, stream>>>(part, nparts);
    k_write_ptr<<<nparts, 256, 0, stream>>>(cnt, part, ptr, cursor, n_nodes, n_edges);
    k_build<<<eblocks, 256, 0, stream>>>(src, dst, cursor, eidx, n_edges);

    const int mblocks0 = (n_nodes + 31) / 32;
    const int mblocks  = (n_nodes + 63) / 64;
    const int ablocks  = (n_nodes * 32 + 255) / 256;

    // ---- Layer 0 ----
    k_layer0<<<mblocks0, 256, 0, stream>>>(x, Wn0, bn0, Ws0, A, B0, n_nodes);
    k_aggregate<<<ablocks, 256, 0, stream>>>(ptr, eidx, A, B0, n_nodes);

    // ---- Layers 1..3 ----
    float* cur = B0;
    float* nxt = B1;
    for (int l = 0; l < 3; ++l) {
        k_layer<<<mblocks, 256, 0, stream>>>(cur, Wn + l * 1024, bn + l * 32,
                                             Ws + l * 1024, A, nxt, n_nodes);
        k_aggregate<<<ablocks, 256, 0, stream>>>(ptr, eidx, A, nxt, n_nodes);
        float* t = cur; cur = nxt; nxt = t;
    }

    // ---- Pool + head ----
    k_pool<<<n_graphs, 256, 0, stream>>>(cur, gids, hg, n_nodes);
    k_head<<<(n_graphs + 63) / 64, 64, 0, stream>>>(hg, Wfc1, bfc1, Wout, bout,
                                                    (float*)d_out, n_graphs);
}